// Round 3
// baseline (302.803 us; speedup 1.0000x reference)
//
#include <hip/hip_runtime.h>

// ---------------------------------------------------------------------------
// VisionEncoder (PASSING since R12): project -> SAT -> fused pool/LN/GEMM2.
// V4 coordinate semantics (XLA reciprocal-multiply) verified.
//
// R17: single persistent kernel. Evidence: R1's K1 profile showed all pipes
//   >95% idle (MfmaUtil 3.3%, VALUBusy 4.4%, 551 GB/s) and R2's big K1
//   restructure moved total only -4us -> the time is in per-dispatch
//   overhead + low-concurrency tails of 5 serialized kernels, not kernel
//   bodies. Fuse everything into ONE 256-block x 512-thread kernel
//   (co-resident: 1 block/CU) with device-scope atomic grid barriers
//   (AGENT-scope atomics + __threadfence -> L2 writeback/invalidate across
//   XCDs). Ctrl word zeroed by hipMemsetAsync (capturable memset node).
//   - phase 0: W1 -> W1T hi/lo bf16 (RNE Dekker split, same as R16)
//   - phase 1: MFMA GEMM, no split-K, wave-tile 16 rows x 64 cols, full K,
//     686 wave-tasks spread w*256+b across all CUs, 2-ahead A prefetch
//   - phase 2: x-scan U -> SAT rows (148 wave-tasks, unroll-8 pipelined)
//   - phase 3: y-scan SAT in place (150 wave-tasks, unroll-8)
//   - phase 4: pool/LN/GEMM2, 16 boxes/block, 512-thread variant
// ---------------------------------------------------------------------------

#define HD   128
#define NBLK 256
#define NTHR 512

typedef __attribute__((ext_vector_type(8))) short bf16x8;
typedef __attribute__((ext_vector_type(4))) float f32x4;

__device__ __forceinline__ int decode_dim(const int* p, int fallback) {
    if (p == nullptr) return fallback;
    int vi = *p;
    if (vi >= 1 && vi <= 1000000) return vi;
    float vf = __int_as_float(vi);
    if (vf >= 1.0f && vf <= 1000000.0f) return (int)vf;
    return fallback;
}

// V4 (verified R12): trunc( fl32( fl32(x * fl32(1/W)) * n ) ), bit-exact via
// f64; optnone so no fast-math rewrite can touch it.
__attribute__((noinline, optnone))
__device__ int coord_map(int x, int W, int n) {
    double rd = 1.0 / (double)W;
    float r = (float)rd;
    double qd = (double)x * (double)r;
    float q = (float)qd;
    double pd = (double)q * (double)n;
    float p = (float)pd;
    return (int)p;
}

// round-to-nearest-even fp32 -> bf16 (as raw u16)
__device__ __forceinline__ unsigned short bf16_rne(float x) {
    unsigned u = __float_as_uint(x);
    unsigned r = u + 0x7fffu + ((u >> 16) & 1u);
    return (unsigned short)(r >> 16);
}

// Grid barrier: sense-reversing generation counter. All 256 blocks are
// co-resident (1/CU), AGENT-scope atomics are cross-XCD coherent, and the
// __threadfence pair gives release (L2 writeback) / acquire (L1/L2 inv).
__device__ __forceinline__ void gbar(int* cnt, int* gen) {
    __syncthreads();
    if (threadIdx.x == 0) {
        __threadfence();                                   // release
        int g = __hip_atomic_load(gen, __ATOMIC_RELAXED,
                                  __HIP_MEMORY_SCOPE_AGENT);
        int a = __hip_atomic_fetch_add(cnt, 1, __ATOMIC_ACQ_REL,
                                       __HIP_MEMORY_SCOPE_AGENT);
        if (a == NBLK - 1) {
            __hip_atomic_store(cnt, 0, __ATOMIC_RELAXED,
                               __HIP_MEMORY_SCOPE_AGENT);
            __hip_atomic_store(gen, g + 1, __ATOMIC_RELEASE,
                               __HIP_MEMORY_SCOPE_AGENT);
        } else {
            while (__hip_atomic_load(gen, __ATOMIC_RELAXED,
                                     __HIP_MEMORY_SCOPE_AGENT) == g)
                __builtin_amdgcn_s_sleep(16);
        }
        __threadfence();                                   // acquire
    }
    __syncthreads();
}

// One K-subtile of the phase-1 GEMM: split A (8 f32 -> bf16 hi/lo) and
// accumulate 4 n-tiles x (hi*hi + lo*hi + hi*lo).
#define STEP(A0, A1, KT) do {                                               \
    bf16x8 bhv[4], blv[4];                                                  \
    _Pragma("unroll")                                                       \
    for (int n = 0; n < 4; ++n) {                                           \
        bhv[n] = *(const bf16x8*)(bh0 + (size_t)(n * 16) * E + (KT));       \
        blv[n] = *(const bf16x8*)(bl0 + (size_t)(n * 16) * E + (KT));       \
    }                                                                       \
    float av[8] = {(A0).x, (A0).y, (A0).z, (A0).w,                          \
                   (A1).x, (A1).y, (A1).z, (A1).w};                         \
    bf16x8 ahi, alo;                                                        \
    _Pragma("unroll")                                                       \
    for (int j = 0; j < 8; ++j) {                                           \
        unsigned h = bf16_rne(av[j]);                                       \
        ahi[j] = (short)h;                                                  \
        float l = av[j] - __uint_as_float(h << 16);                         \
        alo[j] = (short)bf16_rne(l);                                        \
    }                                                                       \
    _Pragma("unroll")                                                       \
    for (int n = 0; n < 4; ++n) {                                           \
        acc[n] = __builtin_amdgcn_mfma_f32_16x16x32_bf16(ahi, bhv[n],       \
                                                         acc[n], 0, 0, 0); \
        acc[n] = __builtin_amdgcn_mfma_f32_16x16x32_bf16(alo, bhv[n],       \
                                                         acc[n], 0, 0, 0); \
        acc[n] = __builtin_amdgcn_mfma_f32_16x16x32_bf16(ahi, blv[n],       \
                                                         acc[n], 0, 0, 0); \
    }                                                                       \
} while (0)

__global__ __launch_bounds__(NTHR, 1) void fused_all(
    const float* __restrict__ T, const int* __restrict__ bboxes,
    const int* __restrict__ pH, const int* __restrict__ pW,
    const float* __restrict__ W1, const float* __restrict__ b1,
    const float* __restrict__ gamma, const float* __restrict__ beta,
    const float* __restrict__ W2, const float* __restrict__ b2,
    float* __restrict__ out,
    float* S, float* U, unsigned short* Whi, unsigned short* Wlo,
    int* cnt, int* gen,
    int P, int E, int Nb, int npw, int nph, int fbW, int fbH)
{
    __shared__ float sh_tile[64][65];          // phase 0
    __shared__ float hs[16][HD + 1];           // phase 4
    __shared__ float Bs[32][HD];
    __shared__ float red_s[16][33], red_q[16][33];
    __shared__ int   cI11[16], cI12[16], cI21[16], cI22[16];
    __shared__ float cCnt[16];
    __shared__ float mu_s[16], rs_s[16];

    int t = threadIdx.x;
    int b = blockIdx.x;
    int w = t >> 6;
    int lane = t & 63;

    // ---------------- phase 0: split W1 -> Whi/Wlo (transposed) -----------
    {
        int ntile0 = (E >> 6) * (HD >> 6);     // 32 tiles of 64k x 64n
        for (int tb = b; tb < ntile0; tb += NBLK) {
            int k0 = (tb >> 1) * 64, n0 = (tb & 1) * 64;
            if (t < 256) {
                int r = t >> 4, c4 = (t & 15) * 4;
#pragma unroll
                for (int i = 0; i < 4; ++i) {
                    int kr = r + i * 16;
                    *(float4*)&sh_tile[kr][c4] =
                        *(const float4*)&W1[(size_t)(k0 + kr) * HD + n0 + c4];
                }
            }
            __syncthreads();
            if (t < 256) {
                int nl = t >> 2, kq = (t & 3) * 16;
                unsigned hp[8], lp[8];
#pragma unroll
                for (int j = 0; j < 8; ++j) {
                    float x0 = sh_tile[kq + 2 * j][nl];
                    float x1 = sh_tile[kq + 2 * j + 1][nl];
                    unsigned h0 = bf16_rne(x0);
                    unsigned h1 = bf16_rne(x1);
                    float l0 = x0 - __uint_as_float(h0 << 16);
                    float l1 = x1 - __uint_as_float(h1 << 16);
                    hp[j] = h0 | ((unsigned)h1 << 16);
                    lp[j] = (unsigned)bf16_rne(l0) |
                            ((unsigned)bf16_rne(l1) << 16);
                }
                size_t off = (size_t)(n0 + nl) * E + k0 + kq;
                *(uint4*)(Whi + off)     = make_uint4(hp[0], hp[1], hp[2], hp[3]);
                *(uint4*)(Whi + off + 8) = make_uint4(hp[4], hp[5], hp[6], hp[7]);
                *(uint4*)(Wlo + off)     = make_uint4(lp[0], lp[1], lp[2], lp[3]);
                *(uint4*)(Wlo + off + 8) = make_uint4(lp[4], lp[5], lp[6], lp[7]);
            }
            __syncthreads();
        }
    }
    gbar(cnt, gen);

    // ---------------- phase 1: GEMM T @ W1 -> U (full K, no split) --------
    // wave-tile = 16 rows x 64 cols; task = w*256 + b spreads tasks across
    // all CUs first. A: direct global (row=lane&15, k=(lane>>4)*8+j),
    // 2-ahead prefetch. B: 16B loads from L2-resident W1T hi/lo.
    // C/D layout (verified m89/m91): col = lane&15, row = (lane>>4)*4 + reg.
    {
        int ntasks = ((P + 15) >> 4) * 2;
        for (int task = w * NBLK + b; task < ntasks; task += NBLK * 8) {
            int rt = task >> 1, ch = task & 1;
            int row0 = rt * 16, col0 = ch * 64;
            int lr = lane & 15, lkq = (lane >> 4) * 8;
            int arow = row0 + lr; if (arow >= P) arow = P - 1;
            const float* ap = T + (size_t)arow * E + lkq;
            const unsigned short* bh0 = Whi + (size_t)(col0 + lr) * E + lkq;
            const unsigned short* bl0 = Wlo + (size_t)(col0 + lr) * E + lkq;

            f32x4 acc[4];
#pragma unroll
            for (int n = 0; n < 4; ++n) acc[n] = (f32x4){0.f, 0.f, 0.f, 0.f};

            float4 pa0 = *(const float4*)(ap);
            float4 pa1 = *(const float4*)(ap + 4);
            float4 qa0 = *(const float4*)(ap + 32);
            float4 qa1 = *(const float4*)(ap + 36);

            for (int kt = 0; kt < E; kt += 64) {
                float4 na0 = pa0, na1 = pa1, ma0 = qa0, ma1 = qa1;
                if (kt + 64 < E) {
                    na0 = *(const float4*)(ap + kt + 64);
                    na1 = *(const float4*)(ap + kt + 68);
                }
                if (kt + 96 < E) {
                    ma0 = *(const float4*)(ap + kt + 96);
                    ma1 = *(const float4*)(ap + kt + 100);
                }
                STEP(pa0, pa1, kt);
                STEP(qa0, qa1, kt + 32);
                pa0 = na0; pa1 = na1; qa0 = ma0; qa1 = ma1;
            }

            int cr0 = row0 + (lane >> 4) * 4;
            int cc  = lane & 15;
#pragma unroll
            for (int n = 0; n < 4; ++n) {
#pragma unroll
                for (int r = 0; r < 4; ++r) {
                    int p = cr0 + r;
                    if (p < P)
                        U[(size_t)p * HD + col0 + n * 16 + cc] = acc[n][r];
                }
            }
        }
    }
    gbar(cnt, gen);

    // ---------------- phase 2: x-scan U -> SAT rows (col-0 border) --------
    {
        int nsc = nph * 2;
        for (int task = w * NBLK + b; task < nsc; task += NBLK * 8) {
            int y = task >> 1, chalf = task & 1;
            int c = chalf * 64 + lane;
            const float* ub = U + (size_t)y * npw * HD + c;
            float* Sy = S + (size_t)(y + 1) * (npw + 1) * HD + c;
            Sy[0] = 0.f;
            float acc = 0.f;
            int x = 0;
            for (; x + 8 <= npw; x += 8) {
                float v0 = ub[(size_t)(x + 0) * HD];
                float v1 = ub[(size_t)(x + 1) * HD];
                float v2 = ub[(size_t)(x + 2) * HD];
                float v3 = ub[(size_t)(x + 3) * HD];
                float v4 = ub[(size_t)(x + 4) * HD];
                float v5 = ub[(size_t)(x + 5) * HD];
                float v6 = ub[(size_t)(x + 6) * HD];
                float v7 = ub[(size_t)(x + 7) * HD];
                acc += v0; Sy[(size_t)(x + 1) * HD] = acc;
                acc += v1; Sy[(size_t)(x + 2) * HD] = acc;
                acc += v2; Sy[(size_t)(x + 3) * HD] = acc;
                acc += v3; Sy[(size_t)(x + 4) * HD] = acc;
                acc += v4; Sy[(size_t)(x + 5) * HD] = acc;
                acc += v5; Sy[(size_t)(x + 6) * HD] = acc;
                acc += v6; Sy[(size_t)(x + 7) * HD] = acc;
                acc += v7; Sy[(size_t)(x + 8) * HD] = acc;
            }
            for (; x < npw; ++x) {
                acc += ub[(size_t)x * HD];
                Sy[(size_t)(x + 1) * HD] = acc;
            }
        }
    }
    gbar(cnt, gen);

    // ---------------- phase 3: y-scan SAT in place (row-0 border) ---------
    {
        int nsc = (npw + 1) * 2;
        size_t stride = (size_t)(npw + 1) * HD;
        for (int task = w * NBLK + b; task < nsc; task += NBLK * 8) {
            int x = task >> 1, chalf = task & 1;
            int c = chalf * 64 + lane;
            float* p0 = S + (size_t)x * HD + c;
            p0[0] = 0.f;
            float acc = 0.f;
            int y = 1;
            for (; y + 8 <= nph + 1; y += 8) {
                float v0 = p0[(size_t)(y + 0) * stride];
                float v1 = p0[(size_t)(y + 1) * stride];
                float v2 = p0[(size_t)(y + 2) * stride];
                float v3 = p0[(size_t)(y + 3) * stride];
                float v4 = p0[(size_t)(y + 4) * stride];
                float v5 = p0[(size_t)(y + 5) * stride];
                float v6 = p0[(size_t)(y + 6) * stride];
                float v7 = p0[(size_t)(y + 7) * stride];
                acc += v0; p0[(size_t)(y + 0) * stride] = acc;
                acc += v1; p0[(size_t)(y + 1) * stride] = acc;
                acc += v2; p0[(size_t)(y + 2) * stride] = acc;
                acc += v3; p0[(size_t)(y + 3) * stride] = acc;
                acc += v4; p0[(size_t)(y + 4) * stride] = acc;
                acc += v5; p0[(size_t)(y + 5) * stride] = acc;
                acc += v6; p0[(size_t)(y + 6) * stride] = acc;
                acc += v7; p0[(size_t)(y + 7) * stride] = acc;
            }
            for (; y <= nph; ++y) {
                acc += p0[(size_t)y * stride];
                p0[(size_t)y * stride] = acc;
            }
        }
    }
    gbar(cnt, gen);

    // ---------------- phase 4: pool + LN + ReLU + GEMM2 -------------------
    // 16 boxes per block-task, 512 threads: c = t&127, rh = t>>7 owns 4 rows.
    {
        int nbt = (Nb + 15) >> 4;
        int c  = t & 127;
        int rh = t >> 7;                       // 0..3
        for (int bb = b; bb < nbt; bb += NBLK) {
            int row0 = bb * 16;
            if (t < 16) {
                int bx = row0 + t; if (bx >= Nb) bx = Nb - 1;
                int x1 = bboxes[bx * 4 + 0];
                int y1 = bboxes[bx * 4 + 1];
                int x2 = bboxes[bx * 4 + 2];
                int y2 = bboxes[bx * 4 + 3];
                int Wi = decode_dim(pW, fbW);
                int Hi = decode_dim(pH, fbH);
                int px1 = coord_map(x1, Wi, npw);
                int px2 = coord_map(x2, Wi, npw);
                int py1 = coord_map(y1, Hi, nph);
                int py2 = coord_map(y2, Hi, nph);
                px1 = min(max(px1, 0), npw - 1);
                px2 = max(px1 + 1, min(px2, npw));
                py1 = min(max(py1, 0), nph - 1);
                py2 = max(py1 + 1, min(py2, nph));
                int st = npw + 1;
                cI11[t] = (py1 * st + px1) * HD;
                cI12[t] = (py1 * st + px2) * HD;
                cI21[t] = (py2 * st + px1) * HD;
                cI22[t] = (py2 * st + px2) * HD;
                cCnt[t] = (float)((py2 - py1) * (px2 - px1));
            }
            __syncthreads();

            float bias1 = b1[c];
            float hv[4];
#pragma unroll
            for (int r = 0; r < 4; ++r) {
                int row = rh * 4 + r;
                float s = S[cI22[row] + c] - S[cI12[row] + c]
                        - S[cI21[row] + c] + S[cI11[row] + c];
                hv[r] = s / cCnt[row] + bias1;
                hs[row][c] = hv[r];
            }
            __syncthreads();

            // LN stats: 32 groups of 4 elements per row
            {
                int sr = t & 15;               // row
                int sg = t >> 4;               // group 0..31
                float ps = 0.f, pq = 0.f;
#pragma unroll
                for (int i = 0; i < 4; ++i) {
                    float v = hs[sr][sg * 4 + i];
                    ps += v; pq += v * v;
                }
                red_s[sr][sg] = ps; red_q[sr][sg] = pq;
            }
            __syncthreads();
            if (t < 16) {
                float s = 0.f, q = 0.f;
#pragma unroll
                for (int i = 0; i < 32; ++i) { s += red_s[t][i]; q += red_q[t][i]; }
                float m = s * (1.0f / HD);
                float v = q * (1.0f / HD) - m * m;
                mu_s[t] = m;
                rs_s[t] = rsqrtf(v + 1e-5f);
            }
            __syncthreads();

            float g = gamma[c], be = beta[c];
#pragma unroll
            for (int r = 0; r < 4; ++r) {
                int row = rh * 4 + r;
                float x = (hv[r] - mu_s[row]) * rs_s[row] * g + be;
                hs[row][c] = fmaxf(x, 0.f);
            }
            __syncthreads();

            float bias2 = b2[c];
            float acc2[4];
#pragma unroll
            for (int r = 0; r < 4; ++r) acc2[r] = bias2;
            for (int k0 = 0; k0 < HD; k0 += 32) {
#pragma unroll
                for (int i = 0; i < 8; ++i) {
                    int idx = t + i * 512;
                    int kk = idx >> 7, cc2 = idx & 127;
                    Bs[kk][cc2] = W2[(size_t)(k0 + kk) * HD + cc2];
                }
                __syncthreads();
#pragma unroll
                for (int kk = 0; kk < 32; ++kk) {
                    float bv = Bs[kk][c];
#pragma unroll
                    for (int r = 0; r < 4; ++r)
                        acc2[r] += hs[rh * 4 + r][k0 + kk] * bv;
                }
                __syncthreads();
            }

#pragma unroll
            for (int r = 0; r < 4; ++r) {
                int rg = row0 + rh * 4 + r;
                if (rg < Nb) out[(size_t)rg * HD + c] = acc2[r];
            }
            __syncthreads();
        }
    }
}

extern "C" void kernel_launch(void* const* d_in, const int* in_sizes, int n_in,
                              void* d_out, int out_size, void* d_ws, size_t ws_size,
                              hipStream_t stream) {
    int iT = 0, iB = 1, iH = 2, iW = 3, iW1 = 4, ib1 = 5, ig = 6, ibe = 7,
        iW2 = 8, ib2 = 9;
    bool has_scalars = (n_in >= 10 && in_sizes[2] == 1 && in_sizes[3] == 1);
    if (!has_scalars) { iW1 = 2; ib1 = 3; ig = 4; ibe = 5; iW2 = 6; ib2 = 7; }

    const float* tokens = (const float*)d_in[iT];
    const int*   bboxes = (const int*)d_in[iB];
    const int*   pH     = has_scalars ? (const int*)d_in[iH] : nullptr;
    const int*   pW     = has_scalars ? (const int*)d_in[iW] : nullptr;
    const float* W1     = (const float*)d_in[iW1];
    const float* b1     = (const float*)d_in[ib1];
    const float* gamma  = (const float*)d_in[ig];
    const float* beta   = (const float*)d_in[ibe];
    const float* W2     = (const float*)d_in[iW2];
    const float* b2     = (const float*)d_in[ib2];
    float* out = (float*)d_out;

    int Hd = in_sizes[ib1];               // 128
    int E  = in_sizes[iW1] / Hd;          // 1024
    int Nb = in_sizes[iB] / 4;            // 4096
    int P  = in_sizes[iT] / E;            // 5476
    int npw = 1;
    while ((npw + 1) * (npw + 1) <= P) ++npw;  // 74
    int nph = P / npw;
    (void)out_size; (void)ws_size;

    // Workspace: ctrl(256B) | S (2.88 MB) | U (2.8 MB) | W1T hi/lo (512 KB)
    int* ctrl = (int*)d_ws;
    float* S = (float*)((char*)d_ws + 256);
    size_t s_elems = ((size_t)(nph + 1) * (npw + 1) * HD + 255) & ~(size_t)255;
    float* U = S + s_elems;
    size_t u_elems = ((size_t)P * HD + 255) & ~(size_t)255;
    unsigned short* Whi = (unsigned short*)(U + u_elems);
    unsigned short* Wlo = Whi + (size_t)E * HD;

    hipMemsetAsync(ctrl, 0, 64, stream);   // zero barrier cnt/gen
    fused_all<<<dim3(NBLK), dim3(NTHR), 0, stream>>>(
        tokens, bboxes, pH, pW, W1, b1, gamma, beta, W2, b2, out,
        S, U, Whi, Wlo, ctrl, ctrl + 1,
        P, E, Nb, npw, nph, 14 * npw, 14 * nph);
}

// Round 4
// 148.637 us; speedup vs baseline: 2.0372x; 2.0372x over previous
//
#include <hip/hip_runtime.h>

// ---------------------------------------------------------------------------
// VisionEncoder (PASSING since R12): project -> SAT -> fused pool/LN/GEMM2.
// V4 coordinate semantics (XLA reciprocal-multiply) verified.
//
// R18: back to multi-kernel (R3's persistent kernel + device-scope fences
//   triggered ~230MB of L3 poison-writeback traffic -> 245us; grid barriers
//   are a no-go in this harness). Changes vs R2 (145.4us, passing):
//   - K1: all-A burst load (8 float4 upfront) + B reg double-buffer one
//     K-step ahead. MFMA order per acc unchanged -> bit-identical results.
//     C written to U^T layout [ks][c][p] as float4 (consecutive p per lane).
//   - K2+K3 merged into ONE SAT kernel: block = channel, coalesced partial
//     sums from U^T, full 2D scan in LDS (same add order), S kept [y][x][c]
//     for K4's gathers. 5 -> 4 dispatches, no serial tiny-grid scans.
//   - K0, K4 unchanged (verified).
// ---------------------------------------------------------------------------

#define HD   128
#define SPLITK 8

typedef __attribute__((ext_vector_type(8))) short bf16x8;
typedef __attribute__((ext_vector_type(4))) float f32x4;

__device__ __forceinline__ int decode_dim(const int* p, int fallback) {
    if (p == nullptr) return fallback;
    int vi = *p;
    if (vi >= 1 && vi <= 1000000) return vi;
    float vf = __int_as_float(vi);
    if (vf >= 1.0f && vf <= 1000000.0f) return (int)vf;
    return fallback;
}

// V4 (verified R12): trunc( fl32( fl32(x * fl32(1/W)) * n ) ), bit-exact via
// f64; optnone so no fast-math rewrite can touch it.
__attribute__((noinline, optnone))
__device__ int coord_map(int x, int W, int n) {
    double rd = 1.0 / (double)W;
    float r = (float)rd;
    double qd = (double)x * (double)r;
    float q = (float)qd;
    double pd = (double)q * (double)n;
    float p = (float)pd;
    return (int)p;
}

// round-to-nearest-even fp32 -> bf16 (as raw u16)
__device__ __forceinline__ unsigned short bf16_rne(float x) {
    unsigned u = __float_as_uint(x);
    unsigned r = u + 0x7fffu + ((u >> 16) & 1u);
    return (unsigned short)(r >> 16);
}

// ---------------------------------------------------------------------------
// K0: W1[E][HD] fp32 -> W1T_hi/W1T_lo[HD][E] bf16 (RNE Dekker split).
// ---------------------------------------------------------------------------
__global__ __launch_bounds__(256) void split_w1_kernel(
    const float* __restrict__ W1, unsigned short* __restrict__ Whi,
    unsigned short* __restrict__ Wlo, int E)
{
    __shared__ float tile[64][65];
    int t = threadIdx.x;
    int k0 = blockIdx.x * 64, n0 = blockIdx.y * 64;

    int r = t >> 4, c4 = (t & 15) * 4;
#pragma unroll
    for (int i = 0; i < 4; ++i) {
        int kr = r + i * 16;
        *(float4*)&tile[kr][c4] =
            *(const float4*)&W1[(size_t)(k0 + kr) * HD + n0 + c4];
    }
    __syncthreads();

    int nl = t >> 2, kq = (t & 3) * 16;
    unsigned hp[8], lp[8];
#pragma unroll
    for (int j = 0; j < 8; ++j) {
        float x0 = tile[kq + 2 * j][nl];
        float x1 = tile[kq + 2 * j + 1][nl];
        unsigned h0 = bf16_rne(x0);
        unsigned h1 = bf16_rne(x1);
        float l0 = x0 - __uint_as_float(h0 << 16);
        float l1 = x1 - __uint_as_float(h1 << 16);
        hp[j] = h0 | ((unsigned)h1 << 16);
        lp[j] = (unsigned)bf16_rne(l0) | ((unsigned)bf16_rne(l1) << 16);
    }
    size_t off = (size_t)(n0 + nl) * E + k0 + kq;
    *(uint4*)(Whi + off)     = make_uint4(hp[0], hp[1], hp[2], hp[3]);
    *(uint4*)(Whi + off + 8) = make_uint4(hp[4], hp[5], hp[6], hp[7]);
    *(uint4*)(Wlo + off)     = make_uint4(lp[0], lp[1], lp[2], lp[3]);
    *(uint4*)(Wlo + off + 8) = make_uint4(lp[4], lp[5], lp[6], lp[7]);
}

// ---------------------------------------------------------------------------
// K1: MFMA partial GEMM. Block = 32 rows x 128 cols, 4 waves:
//   wave w: rows (w&1)*16, cols (w>>1)*64 (4 n-tiles of 16).
// Burst schedule: all 8 A float4 loads issued upfront (HBM latency paid
// once, 8 in flight); B fragments double-buffered in registers one K-step
// ahead (L2 latency hidden under split+MFMA). MFMA sequence per acc[n] is
// s ascending x {hi*bh, lo*bh, hi*bl} -- identical to R2 (bit-exact).
// C/D layout (verified m89/m91): col = lane&15, row = (lane>>4)*4 + reg.
// Output: U^T layout [ks][c][p], float4 stores (p consecutive per lane;
// P%4==0 and cr0%4==0 so the guard is per-float4).
// ---------------------------------------------------------------------------
__global__ __launch_bounds__(256) void gemm_u_mfma(
    const float* __restrict__ T, const unsigned short* __restrict__ Whi,
    const unsigned short* __restrict__ Wlo, float* __restrict__ U,
    int P, int E)
{
    int t = threadIdx.x;
    int lane = t & 63;
    int w = t >> 6;
    int row0 = blockIdx.x * 32 + (w & 1) * 16;
    int col0 = (w >> 1) * 64;
    int kchunk = E >> 3;                       // E / SPLITK = 128
    int kbase = blockIdx.y * kchunk;
    float* Uo = U + (size_t)blockIdx.y * (size_t)HD * P;

    int lr  = lane & 15;
    int lkq = (lane >> 4) * 8;

    int arow = row0 + lr; if (arow >= P) arow = P - 1;
    const float* ap = T + (size_t)arow * E + kbase + lkq;
    const unsigned short* bh0 = Whi + (size_t)(col0 + lr) * E + kbase + lkq;
    const unsigned short* bl0 = Wlo + (size_t)(col0 + lr) * E + kbase + lkq;

    // burst: all A loads upfront (independent, deep MLP)
    float4 a[8];
#pragma unroll
    for (int s = 0; s < 4; ++s) {
        a[2 * s]     = *(const float4*)(ap + s * 32);
        a[2 * s + 1] = *(const float4*)(ap + s * 32 + 4);
    }

    f32x4 acc[4];
#pragma unroll
    for (int n = 0; n < 4; ++n) acc[n] = (f32x4){0.f, 0.f, 0.f, 0.f};

    // B double-buffer in registers, one K-step ahead
    bf16x8 bh[2][4], bl[2][4];
#pragma unroll
    for (int n = 0; n < 4; ++n) {
        bh[0][n] = *(const bf16x8*)(bh0 + (size_t)(n * 16) * E);
        bl[0][n] = *(const bf16x8*)(bl0 + (size_t)(n * 16) * E);
    }

#pragma unroll
    for (int s = 0; s < 4; ++s) {
        int cur = s & 1, nxt = cur ^ 1;
        if (s < 3) {
#pragma unroll
            for (int n = 0; n < 4; ++n) {
                bh[nxt][n] = *(const bf16x8*)(bh0 + (size_t)(n * 16) * E + (s + 1) * 32);
                bl[nxt][n] = *(const bf16x8*)(bl0 + (size_t)(n * 16) * E + (s + 1) * 32);
            }
        }
        float av[8] = {a[2 * s].x, a[2 * s].y, a[2 * s].z, a[2 * s].w,
                       a[2 * s + 1].x, a[2 * s + 1].y, a[2 * s + 1].z, a[2 * s + 1].w};
        bf16x8 ahi, alo;
#pragma unroll
        for (int j = 0; j < 8; ++j) {
            unsigned h = bf16_rne(av[j]);
            ahi[j] = (short)h;
            float l = av[j] - __uint_as_float(h << 16);
            alo[j] = (short)bf16_rne(l);
        }
#pragma unroll
        for (int n = 0; n < 4; ++n) {
            acc[n] = __builtin_amdgcn_mfma_f32_16x16x32_bf16(ahi, bh[cur][n], acc[n], 0, 0, 0);
            acc[n] = __builtin_amdgcn_mfma_f32_16x16x32_bf16(alo, bh[cur][n], acc[n], 0, 0, 0);
            acc[n] = __builtin_amdgcn_mfma_f32_16x16x32_bf16(ahi, bl[cur][n], acc[n], 0, 0, 0);
        }
    }

    int cr0 = row0 + (lane >> 4) * 4;
    int cc  = lane & 15;
    if (cr0 < P) {                              // P%4==0, cr0%4==0
#pragma unroll
        for (int n = 0; n < 4; ++n) {
            float4 v = make_float4(acc[n][0], acc[n][1], acc[n][2], acc[n][3]);
            *(float4*)&Uo[(size_t)(col0 + n * 16 + cc) * P + cr0] = v;
        }
    }
}

// ---------------------------------------------------------------------------
// K23: SAT build, one channel per block. Coalesced partial-sum reads from
// U^T [ks][c][p]; x-scan then y-scan in LDS (add order identical to the old
// prefix_x/prefix_y pair); store S in [y][x][c] layout for K4's gathers.
// LDS tile stride npw+3 (odd) -> conflict-free column access in the x-scan.
// ---------------------------------------------------------------------------
__global__ __launch_bounds__(512) void sat_kernel(
    const float* __restrict__ U, float* __restrict__ S,
    int P, int npw, int nph)
{
    extern __shared__ float tile[];            // (nph+1) x (npw+3)
    int t = threadIdx.x;
    int c = blockIdx.x;
    int ldt = npw + 3;
    int PP = nph * npw;

    const float* Uc = U + (size_t)c * P;
    size_t ustride = (size_t)HD * P;

    for (int i = t; i < PP; i += 512) {
        float s = Uc[i];
#pragma unroll
        for (int p = 1; p < SPLITK; ++p) s += Uc[(size_t)p * ustride + i];
        int y = i / npw, x = i - y * npw;
        tile[(y + 1) * ldt + (x + 1)] = s;
    }
    if (t <= npw) tile[t] = 0.f;               // row 0 border
    if (t <= nph) tile[t * ldt] = 0.f;         // col 0 border
    __syncthreads();

    if (t < nph) {                             // x-scan row t+1
        int row = (t + 1) * ldt;
        float a = 0.f;
        for (int x = 1; x <= npw; ++x) { a += tile[row + x]; tile[row + x] = a; }
    }
    __syncthreads();

    if (t < npw) {                             // y-scan col t+1
        int col = t + 1;
        float a = 0.f;
        for (int y = 1; y <= nph; ++y) {
            a += tile[y * ldt + col]; tile[y * ldt + col] = a;
        }
    }
    __syncthreads();

    int tot = (nph + 1) * (npw + 1);
    for (int i = t; i < tot; i += 512) {
        int y = i / (npw + 1), x = i - y * (npw + 1);
        S[((size_t)y * (npw + 1) + x) * HD + c] = tile[y * ldt + x];
    }
}

// ---------------------------------------------------------------------------
// K4: 16 boxes x 128 cols; parallel LN stats; fp32 out. (unchanged)
// ---------------------------------------------------------------------------
__global__ __launch_bounds__(256) void pool_proj_kernel(
    const float* __restrict__ S, const int* __restrict__ bboxes,
    const int* __restrict__ pH, const int* __restrict__ pW,
    const float* __restrict__ b1, const float* __restrict__ gamma,
    const float* __restrict__ beta, const float* __restrict__ W2,
    const float* __restrict__ b2, float* __restrict__ out,
    int Nb, int npw, int nph, int fbW, int fbH)
{
    __shared__ float hs[16][HD + 1];
    __shared__ float Bs[32][HD];
    __shared__ float red_s[16][17], red_q[16][17];
    __shared__ int   cI11[16], cI12[16], cI21[16], cI22[16];
    __shared__ float cCnt[16];
    __shared__ float mu_s[16], rs_s[16];

    int t = threadIdx.x;
    int c = t & 127;
    int rh = t >> 7;
    int row0 = blockIdx.x * 16;

    if (t < 16) {
        int b = row0 + t; if (b >= Nb) b = Nb - 1;
        int x1 = bboxes[b * 4 + 0];
        int y1 = bboxes[b * 4 + 1];
        int x2 = bboxes[b * 4 + 2];
        int y2 = bboxes[b * 4 + 3];
        int Wi = decode_dim(pW, fbW);
        int Hi = decode_dim(pH, fbH);
        int px1 = coord_map(x1, Wi, npw);
        int px2 = coord_map(x2, Wi, npw);
        int py1 = coord_map(y1, Hi, nph);
        int py2 = coord_map(y2, Hi, nph);
        px1 = min(max(px1, 0), npw - 1);
        px2 = max(px1 + 1, min(px2, npw));
        py1 = min(max(py1, 0), nph - 1);
        py2 = max(py1 + 1, min(py2, nph));
        int st = npw + 1;
        cI11[t] = (py1 * st + px1) * HD;
        cI12[t] = (py1 * st + px2) * HD;
        cI21[t] = (py2 * st + px1) * HD;
        cI22[t] = (py2 * st + px2) * HD;
        cCnt[t] = (float)((py2 - py1) * (px2 - px1));
    }
    __syncthreads();

    float bias1 = b1[c];
    float hv[8];
#pragma unroll
    for (int r = 0; r < 8; ++r) {
        int row = rh * 8 + r;
        float s = S[cI22[row] + c] - S[cI12[row] + c]
                - S[cI21[row] + c] + S[cI11[row] + c];
        hv[r] = s / cCnt[row] + bias1;
        hs[row][c] = hv[r];
    }
    __syncthreads();

    // parallel LN stats: 16 threads per row, 8 elements each
    {
        int sr = t & 15;           // row
        int sg = t >> 4;           // group 0..15
        float ps = 0.f, pq = 0.f;
#pragma unroll
        for (int i = 0; i < 8; ++i) {
            float v = hs[sr][sg * 8 + i];
            ps += v; pq += v * v;
        }
        red_s[sr][sg] = ps; red_q[sr][sg] = pq;
    }
    __syncthreads();
    if (t < 16) {
        float s = 0.f, q = 0.f;
#pragma unroll
        for (int i = 0; i < 16; ++i) { s += red_s[t][i]; q += red_q[t][i]; }
        float m = s * (1.0f / HD);
        float v = q * (1.0f / HD) - m * m;
        mu_s[t] = m;
        rs_s[t] = rsqrtf(v + 1e-5f);
    }
    __syncthreads();

    float g = gamma[c], be = beta[c];
#pragma unroll
    for (int r = 0; r < 8; ++r) {
        int row = rh * 8 + r;
        float x = (hv[r] - mu_s[row]) * rs_s[row] * g + be;
        hs[row][c] = fmaxf(x, 0.f);
    }
    __syncthreads();

    float bias2 = b2[c];
    float acc2[8];
#pragma unroll
    for (int r = 0; r < 8; ++r) acc2[r] = bias2;
    for (int k0 = 0; k0 < HD; k0 += 32) {
#pragma unroll
        for (int i = 0; i < 16; ++i) {
            int idx = t + i * 256;
            int kk = idx >> 7, cc = idx & 127;
            Bs[kk][cc] = W2[(size_t)(k0 + kk) * HD + cc];
        }
        __syncthreads();
#pragma unroll
        for (int kk = 0; kk < 32; ++kk) {
            float bv = Bs[kk][c];
#pragma unroll
            for (int r = 0; r < 8; ++r)
                acc2[r] += hs[rh * 8 + r][k0 + kk] * bv;
        }
        __syncthreads();
    }

#pragma unroll
    for (int r = 0; r < 8; ++r) {
        int rg = row0 + rh * 8 + r;
        if (rg < Nb) out[(size_t)rg * HD + c] = acc2[r];
    }
}

extern "C" void kernel_launch(void* const* d_in, const int* in_sizes, int n_in,
                              void* d_out, int out_size, void* d_ws, size_t ws_size,
                              hipStream_t stream) {
    int iT = 0, iB = 1, iH = 2, iW = 3, iW1 = 4, ib1 = 5, ig = 6, ibe = 7,
        iW2 = 8, ib2 = 9;
    bool has_scalars = (n_in >= 10 && in_sizes[2] == 1 && in_sizes[3] == 1);
    if (!has_scalars) { iW1 = 2; ib1 = 3; ig = 4; ibe = 5; iW2 = 6; ib2 = 7; }

    const float* tokens = (const float*)d_in[iT];
    const int*   bboxes = (const int*)d_in[iB];
    const int*   pH     = has_scalars ? (const int*)d_in[iH] : nullptr;
    const int*   pW     = has_scalars ? (const int*)d_in[iW] : nullptr;
    const float* W1     = (const float*)d_in[iW1];
    const float* b1     = (const float*)d_in[ib1];
    const float* gamma  = (const float*)d_in[ig];
    const float* beta   = (const float*)d_in[ibe];
    const float* W2     = (const float*)d_in[iW2];
    const float* b2     = (const float*)d_in[ib2];
    float* out = (float*)d_out;

    int Hd = in_sizes[ib1];               // 128
    int E  = in_sizes[iW1] / Hd;          // 1024
    int Nb = in_sizes[iB] / 4;            // 4096
    int P  = in_sizes[iT] / E;            // 5476
    int npw = 1;
    while ((npw + 1) * (npw + 1) <= P) ++npw;  // 74
    int nph = P / npw;
    (void)out_size; (void)ws_size;

    // Workspace: S (2.88 MB) | U^T [8][128][P] (22.4 MB) | W1T hi/lo (512 KB)
    float* S = (float*)d_ws;
    size_t s_elems = ((size_t)(nph + 1) * (npw + 1) * HD + 255) & ~(size_t)255;
    float* U = S + s_elems;
    size_t u_elems = ((size_t)SPLITK * HD * P + 255) & ~(size_t)255;
    unsigned short* Whi = (unsigned short*)(U + u_elems);
    unsigned short* Wlo = Whi + (size_t)E * HD;

    split_w1_kernel<<<dim3(E / 64, HD / 64), dim3(256), 0, stream>>>(
        W1, Whi, Wlo, E);

    int mtiles = (P + 31) / 32;
    gemm_u_mfma<<<dim3(mtiles, SPLITK), dim3(256), 0, stream>>>(
        tokens, Whi, Wlo, U, P, E);

    size_t sat_lds = (size_t)(nph + 1) * (npw + 3) * sizeof(float);
    sat_kernel<<<dim3(HD), dim3(512), sat_lds, stream>>>(
        U, S, P, npw, nph);

    pool_proj_kernel<<<dim3((Nb + 15) / 16), dim3(256), 0, stream>>>(
        S, bboxes, pH, pW, b1, gamma, beta, W2, b2, out, Nb, npw, nph,
        14 * npw, 14 * nph);
}

// Round 5
// 145.431 us; speedup vs baseline: 2.0821x; 1.0220x over previous
//
#include <hip/hip_runtime.h>

// ---------------------------------------------------------------------------
// VisionEncoder (PASSING since R12): project -> SAT -> fused pool/LN/GEMM2.
// V4 coordinate semantics (XLA reciprocal-multiply) verified.
//
// R19: dispatch-count reduction (5 rounds of body changes left total pinned
//   138-149us; R3 calibrates fixed cost: 1 dispatch -> total = kernel + 58us
//   [43 fill + ~15 replay]; so R4 carried ~70-90us of gaps/tails). Sync-free
//   minimum is 3 dispatches:
//   D1 gemm_u_mfma: K0 absorbed -- W1 fp32 read direct (L2-resident), RNE
//      hi/lo split per-wave in-register (bit-identical split values), full
//      K=1024 (no split-K -> U written once, 2.8MB), 343 blocks x 256thr,
//      block = 16 rows x 128 cols, wave = 16 rows x 32 cols (2 n-tiles),
//      1-step A/B register prefetch.
//   D2 sat_kernel: R4's verified SAT minus the 8-partial sum (single U).
//   D3 pool_proj: unchanged (verified).
//   No device-scope fences anywhere (R3 lesson: fences after the 268MB
//   poison fill flush dirty L2 -> 138MB writeback storm).
// ---------------------------------------------------------------------------

#define HD 128

typedef __attribute__((ext_vector_type(8))) short bf16x8;
typedef __attribute__((ext_vector_type(4))) float f32x4;

__device__ __forceinline__ int decode_dim(const int* p, int fallback) {
    if (p == nullptr) return fallback;
    int vi = *p;
    if (vi >= 1 && vi <= 1000000) return vi;
    float vf = __int_as_float(vi);
    if (vf >= 1.0f && vf <= 1000000.0f) return (int)vf;
    return fallback;
}

// V4 (verified R12): trunc( fl32( fl32(x * fl32(1/W)) * n ) ), bit-exact via
// f64; optnone so no fast-math rewrite can touch it.
__attribute__((noinline, optnone))
__device__ int coord_map(int x, int W, int n) {
    double rd = 1.0 / (double)W;
    float r = (float)rd;
    double qd = (double)x * (double)r;
    float q = (float)qd;
    double pd = (double)q * (double)n;
    float p = (float)pd;
    return (int)p;
}

// round-to-nearest-even fp32 -> bf16 (as raw u16)
__device__ __forceinline__ unsigned short bf16_rne(float x) {
    unsigned u = __float_as_uint(x);
    unsigned r = u + 0x7fffu + ((u >> 16) & 1u);
    return (unsigned short)(r >> 16);
}

// ---------------------------------------------------------------------------
// D1: MFMA GEMM, full K, W-split fused (in-register, per-wave).
// Block = 16 rows x 128 cols, 4 waves; wave w owns cols [w*32, w*32+32)
// = 2 n-tiles of 16. A frag: T direct (row = lane&15, k = (lane>>4)*8+j),
// RNE hi/lo split in-register. B frag: W1 fp32 direct (8 dwords, stride HD,
// L2/L3-resident), RNE hi/lo split in-register -- identical bf16 values to
// the old K0 pre-split. D = Ahi*Bhi + Alo*Bhi + Ahi*Blo per K-step, K-steps
// ascending in ONE MFMA chain (fp32 accum; order differs from split-K+adds,
// tolerance proven >= 3.9e-3 by R1).
// C/D layout (verified m89/m91): col = lane&15, row = (lane>>4)*4 + reg.
// Output U^T [c][p] float4 (P%4==0, cr0%4==0 -> per-quarter guard).
// ---------------------------------------------------------------------------
__global__ __launch_bounds__(256) void gemm_u_mfma(
    const float* __restrict__ T, const float* __restrict__ W1,
    float* __restrict__ U, int P, int E)
{
    int t = threadIdx.x;
    int lane = t & 63;
    int w = t >> 6;                        // wave: cols [w*32, w*32+32)
    int row0 = blockIdx.x * 16;
    int lr  = lane & 15;
    int lkq = (lane >> 4) * 8;

    int arow = row0 + lr; if (arow >= P) arow = P - 1;
    const float* ap = T + (size_t)arow * E + lkq;
    const float* bp = W1 + (size_t)lkq * HD + w * 32 + lr;

    f32x4 acc[2];
    acc[0] = (f32x4){0.f, 0.f, 0.f, 0.f};
    acc[1] = (f32x4){0.f, 0.f, 0.f, 0.f};

    float ac[8], an[8], bc[2][8], bn[2][8];

    {   // preload K-step 0
        float4 a0 = *(const float4*)(ap);
        float4 a1 = *(const float4*)(ap + 4);
        ac[0] = a0.x; ac[1] = a0.y; ac[2] = a0.z; ac[3] = a0.w;
        ac[4] = a1.x; ac[5] = a1.y; ac[6] = a1.z; ac[7] = a1.w;
#pragma unroll
        for (int nn = 0; nn < 2; ++nn)
#pragma unroll
            for (int j = 0; j < 8; ++j)
                bc[nn][j] = bp[(size_t)j * HD + nn * 16];
    }

    for (int kt = 0; kt < E; kt += 32) {
        if (kt + 32 < E) {                 // prefetch next K-step
            float4 a0 = *(const float4*)(ap + kt + 32);
            float4 a1 = *(const float4*)(ap + kt + 36);
            an[0] = a0.x; an[1] = a0.y; an[2] = a0.z; an[3] = a0.w;
            an[4] = a1.x; an[5] = a1.y; an[6] = a1.z; an[7] = a1.w;
#pragma unroll
            for (int nn = 0; nn < 2; ++nn)
#pragma unroll
                for (int j = 0; j < 8; ++j)
                    bn[nn][j] = bp[(size_t)(kt + 32 + j) * HD + nn * 16];
        }

        bf16x8 ahi, alo;
#pragma unroll
        for (int j = 0; j < 8; ++j) {
            unsigned h = bf16_rne(ac[j]);
            ahi[j] = (short)h;
            alo[j] = (short)bf16_rne(ac[j] - __uint_as_float(h << 16));
        }
#pragma unroll
        for (int nn = 0; nn < 2; ++nn) {
            bf16x8 bhi, blo;
#pragma unroll
            for (int j = 0; j < 8; ++j) {
                unsigned h = bf16_rne(bc[nn][j]);
                bhi[j] = (short)h;
                blo[j] = (short)bf16_rne(bc[nn][j] - __uint_as_float(h << 16));
            }
            acc[nn] = __builtin_amdgcn_mfma_f32_16x16x32_bf16(ahi, bhi, acc[nn], 0, 0, 0);
            acc[nn] = __builtin_amdgcn_mfma_f32_16x16x32_bf16(alo, bhi, acc[nn], 0, 0, 0);
            acc[nn] = __builtin_amdgcn_mfma_f32_16x16x32_bf16(ahi, blo, acc[nn], 0, 0, 0);
        }

#pragma unroll
        for (int j = 0; j < 8; ++j) {
            ac[j] = an[j]; bc[0][j] = bn[0][j]; bc[1][j] = bn[1][j];
        }
    }

    int cr0 = row0 + (lane >> 4) * 4;
    int cc  = lane & 15;
    if (cr0 < P) {                         // P%4==0, cr0%4==0
#pragma unroll
        for (int nn = 0; nn < 2; ++nn) {
            float4 v = make_float4(acc[nn][0], acc[nn][1], acc[nn][2], acc[nn][3]);
            *(float4*)&U[(size_t)(w * 32 + nn * 16 + cc) * P + cr0] = v;
        }
    }
}

// ---------------------------------------------------------------------------
// D2: SAT build, one channel per block (verified structure from R18, minus
// the split-K partial sum). Coalesced read from U^T [c][p]; x-scan then
// y-scan in LDS (add order identical to the original prefix pair); store S
// in [y][x][c] layout for D3's gathers. LDS stride npw+3 (odd).
// ---------------------------------------------------------------------------
__global__ __launch_bounds__(512) void sat_kernel(
    const float* __restrict__ U, float* __restrict__ S,
    int P, int npw, int nph)
{
    extern __shared__ float tile[];            // (nph+1) x (npw+3)
    int t = threadIdx.x;
    int c = blockIdx.x;
    int ldt = npw + 3;
    int PP = nph * npw;

    const float* Uc = U + (size_t)c * P;

    for (int i = t; i < PP; i += 512) {
        float s = Uc[i];
        int y = i / npw, x = i - y * npw;
        tile[(y + 1) * ldt + (x + 1)] = s;
    }
    if (t <= npw) tile[t] = 0.f;               // row 0 border
    if (t <= nph) tile[t * ldt] = 0.f;         // col 0 border
    __syncthreads();

    if (t < nph) {                             // x-scan row t+1
        int row = (t + 1) * ldt;
        float a = 0.f;
        for (int x = 1; x <= npw; ++x) { a += tile[row + x]; tile[row + x] = a; }
    }
    __syncthreads();

    if (t < npw) {                             // y-scan col t+1
        int col = t + 1;
        float a = 0.f;
        for (int y = 1; y <= nph; ++y) {
            a += tile[y * ldt + col]; tile[y * ldt + col] = a;
        }
    }
    __syncthreads();

    int tot = (nph + 1) * (npw + 1);
    for (int i = t; i < tot; i += 512) {
        int y = i / (npw + 1), x = i - y * (npw + 1);
        S[((size_t)y * (npw + 1) + x) * HD + c] = tile[y * ldt + x];
    }
}

// ---------------------------------------------------------------------------
// D3: 16 boxes x 128 cols; parallel LN stats; fp32 out. (unchanged)
// ---------------------------------------------------------------------------
__global__ __launch_bounds__(256) void pool_proj_kernel(
    const float* __restrict__ S, const int* __restrict__ bboxes,
    const int* __restrict__ pH, const int* __restrict__ pW,
    const float* __restrict__ b1, const float* __restrict__ gamma,
    const float* __restrict__ beta, const float* __restrict__ W2,
    const float* __restrict__ b2, float* __restrict__ out,
    int Nb, int npw, int nph, int fbW, int fbH)
{
    __shared__ float hs[16][HD + 1];
    __shared__ float Bs[32][HD];
    __shared__ float red_s[16][17], red_q[16][17];
    __shared__ int   cI11[16], cI12[16], cI21[16], cI22[16];
    __shared__ float cCnt[16];
    __shared__ float mu_s[16], rs_s[16];

    int t = threadIdx.x;
    int c = t & 127;
    int rh = t >> 7;
    int row0 = blockIdx.x * 16;

    if (t < 16) {
        int b = row0 + t; if (b >= Nb) b = Nb - 1;
        int x1 = bboxes[b * 4 + 0];
        int y1 = bboxes[b * 4 + 1];
        int x2 = bboxes[b * 4 + 2];
        int y2 = bboxes[b * 4 + 3];
        int Wi = decode_dim(pW, fbW);
        int Hi = decode_dim(pH, fbH);
        int px1 = coord_map(x1, Wi, npw);
        int px2 = coord_map(x2, Wi, npw);
        int py1 = coord_map(y1, Hi, nph);
        int py2 = coord_map(y2, Hi, nph);
        px1 = min(max(px1, 0), npw - 1);
        px2 = max(px1 + 1, min(px2, npw));
        py1 = min(max(py1, 0), nph - 1);
        py2 = max(py1 + 1, min(py2, nph));
        int st = npw + 1;
        cI11[t] = (py1 * st + px1) * HD;
        cI12[t] = (py1 * st + px2) * HD;
        cI21[t] = (py2 * st + px1) * HD;
        cI22[t] = (py2 * st + px2) * HD;
        cCnt[t] = (float)((py2 - py1) * (px2 - px1));
    }
    __syncthreads();

    float bias1 = b1[c];
    float hv[8];
#pragma unroll
    for (int r = 0; r < 8; ++r) {
        int row = rh * 8 + r;
        float s = S[cI22[row] + c] - S[cI12[row] + c]
                - S[cI21[row] + c] + S[cI11[row] + c];
        hv[r] = s / cCnt[row] + bias1;
        hs[row][c] = hv[r];
    }
    __syncthreads();

    // parallel LN stats: 16 threads per row, 8 elements each
    {
        int sr = t & 15;           // row
        int sg = t >> 4;           // group 0..15
        float ps = 0.f, pq = 0.f;
#pragma unroll
        for (int i = 0; i < 8; ++i) {
            float v = hs[sr][sg * 8 + i];
            ps += v; pq += v * v;
        }
        red_s[sr][sg] = ps; red_q[sr][sg] = pq;
    }
    __syncthreads();
    if (t < 16) {
        float s = 0.f, q = 0.f;
#pragma unroll
        for (int i = 0; i < 16; ++i) { s += red_s[t][i]; q += red_q[t][i]; }
        float m = s * (1.0f / HD);
        float v = q * (1.0f / HD) - m * m;
        mu_s[t] = m;
        rs_s[t] = rsqrtf(v + 1e-5f);
    }
    __syncthreads();

    float g = gamma[c], be = beta[c];
#pragma unroll
    for (int r = 0; r < 8; ++r) {
        int row = rh * 8 + r;
        float x = (hv[r] - mu_s[row]) * rs_s[row] * g + be;
        hs[row][c] = fmaxf(x, 0.f);
    }
    __syncthreads();

    float bias2 = b2[c];
    float acc2[8];
#pragma unroll
    for (int r = 0; r < 8; ++r) acc2[r] = bias2;
    for (int k0 = 0; k0 < HD; k0 += 32) {
#pragma unroll
        for (int i = 0; i < 16; ++i) {
            int idx = t + i * 256;
            int kk = idx >> 7, cc = idx & 127;
            Bs[kk][cc] = W2[(size_t)(k0 + kk) * HD + cc];
        }
        __syncthreads();
#pragma unroll
        for (int kk = 0; kk < 32; ++kk) {
            float bv = Bs[kk][c];
#pragma unroll
            for (int r = 0; r < 8; ++r)
                acc2[r] += hs[rh * 8 + r][k0 + kk] * bv;
        }
        __syncthreads();
    }

#pragma unroll
    for (int r = 0; r < 8; ++r) {
        int rg = row0 + rh * 8 + r;
        if (rg < Nb) out[(size_t)rg * HD + c] = acc2[r];
    }
}

extern "C" void kernel_launch(void* const* d_in, const int* in_sizes, int n_in,
                              void* d_out, int out_size, void* d_ws, size_t ws_size,
                              hipStream_t stream) {
    int iT = 0, iB = 1, iH = 2, iW = 3, iW1 = 4, ib1 = 5, ig = 6, ibe = 7,
        iW2 = 8, ib2 = 9;
    bool has_scalars = (n_in >= 10 && in_sizes[2] == 1 && in_sizes[3] == 1);
    if (!has_scalars) { iW1 = 2; ib1 = 3; ig = 4; ibe = 5; iW2 = 6; ib2 = 7; }

    const float* tokens = (const float*)d_in[iT];
    const int*   bboxes = (const int*)d_in[iB];
    const int*   pH     = has_scalars ? (const int*)d_in[iH] : nullptr;
    const int*   pW     = has_scalars ? (const int*)d_in[iW] : nullptr;
    const float* W1     = (const float*)d_in[iW1];
    const float* b1     = (const float*)d_in[ib1];
    const float* gamma  = (const float*)d_in[ig];
    const float* beta   = (const float*)d_in[ibe];
    const float* W2     = (const float*)d_in[iW2];
    const float* b2     = (const float*)d_in[ib2];
    float* out = (float*)d_out;

    int Hd = in_sizes[ib1];               // 128
    int E  = in_sizes[iW1] / Hd;          // 1024
    int Nb = in_sizes[iB] / 4;            // 4096
    int P  = in_sizes[iT] / E;            // 5476
    int npw = 1;
    while ((npw + 1) * (npw + 1) <= P) ++npw;  // 74
    int nph = P / npw;
    (void)out_size; (void)ws_size;

    // Workspace: S (2.88 MB) | U^T [128][P] (2.8 MB)
    float* S = (float*)d_ws;
    size_t s_elems = ((size_t)(nph + 1) * (npw + 1) * HD + 255) & ~(size_t)255;
    float* U = S + s_elems;

    int mtiles = (P + 15) / 16;
    gemm_u_mfma<<<dim3(mtiles), dim3(256), 0, stream>>>(
        tokens, W1, U, P, E);

    size_t sat_lds = (size_t)(nph + 1) * (npw + 3) * sizeof(float);
    sat_kernel<<<dim3(HD), dim3(512), sat_lds, stream>>>(
        U, S, P, npw, nph);

    pool_proj_kernel<<<dim3((Nb + 15) / 16), dim3(256), 0, stream>>>(
        S, bboxes, pH, pW, b1, gamma, beta, W2, b2, out, Nb, npw, nph,
        14 * npw, 14 * nph);
}

// Round 6
// 133.946 us; speedup vs baseline: 2.2606x; 1.0857x over previous
//
#include <hip/hip_runtime.h>

// ---------------------------------------------------------------------------
// VisionEncoder (PASSING since R12, absmax 1.95e-3): project -> SAT -> fused
// pool/LN/GEMM2. V4 coordinate semantics (XLA reciprocal-multiply) verified.
//
// R20: revert to the empirically-fastest R14 pipeline (137.8us; all R15-R19
//   MFMA/fusion rewrites measured 145-149us -- at N=128 the MFMA+Dekker path
//   is ~4us SLOWER than this LDS-tiled VALU gemm, and dispatch gaps proved
//   ~1us each, so 5 dispatches are fine). Single surgical change:
//   gemm_u Bs staging now uses __builtin_amdgcn_global_load_lds width=16
//   (legal: per-wave LDS dest = uniform + lane*16), removing the
//   VGPR round-trip + address VALU from the staging path. As staging is a
//   transpose scatter (per-lane dest) and must stay manual.
//   K1 gemm_u  : 64x128 tile, 8x4 micro, split-K=8 -> 688 blocks;
//                As padded to 65 (bank-conflict fix)
//   K2 prefix_x: grid (nph,2), 64 ch/block, sums 8 partials, x-scan -> SAT
//   K3 prefix_y: grid (npw+1,2), 64 ch/block, y-scan in LDS
//   K4 pool_proj: parallel LN stats (256-thr partial sums + LDS tree)
// ---------------------------------------------------------------------------

#define HD 128
#define SPLITK 8

#define GLOBAL_AS __attribute__((address_space(1)))
#define LDS_AS    __attribute__((address_space(3)))

__device__ __forceinline__ int decode_dim(const int* p, int fallback) {
    if (p == nullptr) return fallback;
    int vi = *p;
    if (vi >= 1 && vi <= 1000000) return vi;
    float vf = __int_as_float(vi);
    if (vf >= 1.0f && vf <= 1000000.0f) return (int)vf;
    return fallback;
}

// V4 (verified R12): trunc( fl32( fl32(x * fl32(1/W)) * n ) ), bit-exact via
// f64; optnone so no fast-math rewrite can touch it.
__attribute__((noinline, optnone))
__device__ int coord_map(int x, int W, int n) {
    double rd = 1.0 / (double)W;
    float r = (float)rd;
    double qd = (double)x * (double)r;
    float q = (float)qd;
    double pd = (double)q * (double)n;
    float p = (float)pd;
    return (int)p;
}

// ---------------------------------------------------------------------------
// K1: partial GEMM, tile 64 rows x 128 cols, K-chunk = E/8.
// ---------------------------------------------------------------------------
__global__ __launch_bounds__(256) void gemm_u_kernel(
    const float* __restrict__ T, const float* __restrict__ W1,
    float* __restrict__ U, int P, int E)
{
    __shared__ float As[32][65];    // [kk][row], pad 65: staging writes 2-way
    __shared__ float Bs[32][HD];    // [kk][col]

    int t  = threadIdx.x;
    int tc = t & 31;                // cols tc*4 .. tc*4+3
    int tr = t >> 5;                // rows tr*8 .. tr*8+7
    int row0 = blockIdx.x * 64;
    int ks   = blockIdx.y;
    int kchunk = E >> 3;            // 128
    int kbase  = ks * kchunk;
    float* Uo = U + (size_t)ks * (size_t)P * HD;

    float acc[8][4];
#pragma unroll
    for (int r = 0; r < 8; ++r)
#pragma unroll
        for (int j = 0; j < 4; ++j) acc[r][j] = 0.f;

    int arow = t >> 2;              // 0..63
    int akq  = (t & 3) * 8;         // 0,8,16,24
    int brow = t >> 5;              // 0..7
    int bc   = (t & 31) * 4;

    for (int kt = 0; kt < kchunk; kt += 32) {
        int k0 = kbase + kt;
        {   // stage B via direct global->LDS DMA (async, drained by barrier).
            // Dest offset for thread t = ((brow+i*8)*128 + bc)*4
            //   = w*1024 + lane*16 + i*4096  -> wave-uniform base + lane*16: OK.
#pragma unroll
            for (int i = 0; i < 4; ++i) {
                int kk = brow + i * 8;
                __builtin_amdgcn_global_load_lds(
                    (const GLOBAL_AS unsigned int*)&W1[(size_t)(k0 + kk) * HD + bc],
                    (LDS_AS unsigned int*)&Bs[kk][bc], 16, 0, 0);
            }
        }
        {   // stage A: T[row0+arow][k0+akq..+7] -> As[k][row] (transpose scatter)
            int rg = row0 + arow; if (rg >= P) rg = P - 1;
            const float* tp = T + (size_t)rg * E + k0 + akq;
            float4 v0 = *(const float4*)tp;
            float4 v1 = *(const float4*)(tp + 4);
            As[akq + 0][arow] = v0.x; As[akq + 1][arow] = v0.y;
            As[akq + 2][arow] = v0.z; As[akq + 3][arow] = v0.w;
            As[akq + 4][arow] = v1.x; As[akq + 5][arow] = v1.y;
            As[akq + 6][arow] = v1.z; As[akq + 7][arow] = v1.w;
        }
        __syncthreads();

#pragma unroll
        for (int kk = 0; kk < 32; ++kk) {
            float4 a0 = *(const float4*)&As[kk][tr * 8];
            float4 a1 = *(const float4*)&As[kk][tr * 8 + 4];
            float4 b  = *(const float4*)&Bs[kk][tc * 4];
            float av[8] = {a0.x, a0.y, a0.z, a0.w, a1.x, a1.y, a1.z, a1.w};
            float bv[4] = {b.x, b.y, b.z, b.w};
#pragma unroll
            for (int r = 0; r < 8; ++r)
#pragma unroll
                for (int j = 0; j < 4; ++j)
                    acc[r][j] += av[r] * bv[j];
        }
        __syncthreads();
    }

#pragma unroll
    for (int r = 0; r < 8; ++r) {
        int p = row0 + tr * 8 + r;
        if (p < P) {
            float4 v = make_float4(acc[r][0], acc[r][1], acc[r][2], acc[r][3]);
            *(float4*)&Uo[(size_t)p * HD + tc * 4] = v;
        }
    }
}

// ---------------------------------------------------------------------------
// K2: block (y, chalf): sum SPLITK partials of row y (74 x 64ch), x-scan,
// write SAT row y+1 (+ col-0 border).
// ---------------------------------------------------------------------------
__global__ __launch_bounds__(256) void prefix_x_kernel(
    const float* __restrict__ U, float* __restrict__ S,
    int P, int npw, int nph)
{
    extern __shared__ float tile[];            // npw*64 floats
    int t = threadIdx.x;
    int y = blockIdx.x;
    int ch0 = blockIdx.y * 64;
    size_t ustride = (size_t)P * HD;
    size_t ubase = (size_t)y * npw * HD + ch0;

    int nj = npw * 16;                         // float4 groups
    for (int j = t; j < nj; j += 256) {
        int x = j >> 4, cq = (j & 15) * 4;
        size_t off = ubase + (size_t)x * HD + cq;
        float4 s = *(const float4*)(U + off);
#pragma unroll
        for (int p = 1; p < SPLITK; ++p) {
            float4 v = *(const float4*)(U + (size_t)p * ustride + off);
            s.x += v.x; s.y += v.y; s.z += v.z; s.w += v.w;
        }
        *(float4*)&tile[x * 64 + cq] = s;
    }
    __syncthreads();

    if (t < 64) {
        int c = t;
        size_t srow = (size_t)(y + 1) * (npw + 1) * HD + ch0;
        S[srow + c] = 0.f;                     // col-0 border
        float acc = 0.f;
        for (int x = 0; x < npw; ++x) {
            acc += tile[x * 64 + c];
            S[srow + (size_t)(x + 1) * HD + c] = acc;
        }
    }
}

// ---------------------------------------------------------------------------
// K3: block (x, chalf): stage column x (y=1..nph) through LDS, y-scan,
// write back (+ row-0 border).
// ---------------------------------------------------------------------------
__global__ __launch_bounds__(256) void prefix_y_kernel(
    float* __restrict__ S, int npw, int nph)
{
    extern __shared__ float tile[];            // nph*64 floats
    int t = threadIdx.x;
    int x = blockIdx.x;
    int ch0 = blockIdx.y * 64;
    size_t stride = (size_t)(npw + 1) * HD;
    size_t base = (size_t)x * HD + ch0;

    int nj = nph * 16;
    for (int j = t; j < nj; j += 256) {
        int y = j >> 4, cq = (j & 15) * 4;
        *(float4*)&tile[y * 64 + cq] =
            *(const float4*)(S + base + (size_t)(y + 1) * stride + cq);
    }
    __syncthreads();

    if (t < 64) {
        int c = t;
        S[base + c] = 0.f;                     // row-0 border
        float acc = 0.f;
        for (int y = 0; y < nph; ++y) {
            acc += tile[y * 64 + c];
            S[base + (size_t)(y + 1) * stride + c] = acc;
        }
    }
}

// ---------------------------------------------------------------------------
// K4: 16 boxes x 128 cols; parallel LN stats; fp32 out.
// ---------------------------------------------------------------------------
__global__ __launch_bounds__(256) void pool_proj_kernel(
    const float* __restrict__ S, const int* __restrict__ bboxes,
    const int* __restrict__ pH, const int* __restrict__ pW,
    const float* __restrict__ b1, const float* __restrict__ gamma,
    const float* __restrict__ beta, const float* __restrict__ W2,
    const float* __restrict__ b2, float* __restrict__ out,
    int Nb, int npw, int nph, int fbW, int fbH)
{
    __shared__ float hs[16][HD + 1];
    __shared__ float Bs[32][HD];
    __shared__ float red_s[16][17], red_q[16][17];
    __shared__ int   cI11[16], cI12[16], cI21[16], cI22[16];
    __shared__ float cCnt[16];
    __shared__ float mu_s[16], rs_s[16];

    int t = threadIdx.x;
    int c = t & 127;
    int rh = t >> 7;
    int row0 = blockIdx.x * 16;

    if (t < 16) {
        int b = row0 + t; if (b >= Nb) b = Nb - 1;
        int x1 = bboxes[b * 4 + 0];
        int y1 = bboxes[b * 4 + 1];
        int x2 = bboxes[b * 4 + 2];
        int y2 = bboxes[b * 4 + 3];
        int Wi = decode_dim(pW, fbW);
        int Hi = decode_dim(pH, fbH);
        int px1 = coord_map(x1, Wi, npw);
        int px2 = coord_map(x2, Wi, npw);
        int py1 = coord_map(y1, Hi, nph);
        int py2 = coord_map(y2, Hi, nph);
        px1 = min(max(px1, 0), npw - 1);
        px2 = max(px1 + 1, min(px2, npw));
        py1 = min(max(py1, 0), nph - 1);
        py2 = max(py1 + 1, min(py2, nph));
        int st = npw + 1;
        cI11[t] = (py1 * st + px1) * HD;
        cI12[t] = (py1 * st + px2) * HD;
        cI21[t] = (py2 * st + px1) * HD;
        cI22[t] = (py2 * st + px2) * HD;
        cCnt[t] = (float)((py2 - py1) * (px2 - px1));
    }
    __syncthreads();

    float bias1 = b1[c];
    float hv[8];
#pragma unroll
    for (int r = 0; r < 8; ++r) {
        int row = rh * 8 + r;
        float s = S[cI22[row] + c] - S[cI12[row] + c]
                - S[cI21[row] + c] + S[cI11[row] + c];
        hv[r] = s / cCnt[row] + bias1;
        hs[row][c] = hv[r];
    }
    __syncthreads();

    // parallel LN stats: 16 threads per row, 8 elements each
    {
        int sr = t & 15;           // row
        int sg = t >> 4;           // group 0..15
        float ps = 0.f, pq = 0.f;
#pragma unroll
        for (int i = 0; i < 8; ++i) {
            float v = hs[sr][sg * 8 + i];
            ps += v; pq += v * v;
        }
        red_s[sr][sg] = ps; red_q[sr][sg] = pq;
    }
    __syncthreads();
    if (t < 16) {
        float s = 0.f, q = 0.f;
#pragma unroll
        for (int i = 0; i < 16; ++i) { s += red_s[t][i]; q += red_q[t][i]; }
        float m = s * (1.0f / HD);
        float v = q * (1.0f / HD) - m * m;
        mu_s[t] = m;
        rs_s[t] = rsqrtf(v + 1e-5f);
    }
    __syncthreads();

    float g = gamma[c], be = beta[c];
#pragma unroll
    for (int r = 0; r < 8; ++r) {
        int row = rh * 8 + r;
        float x = (hv[r] - mu_s[row]) * rs_s[row] * g + be;
        hs[row][c] = fmaxf(x, 0.f);
    }
    __syncthreads();

    float bias2 = b2[c];
    float acc2[8];
#pragma unroll
    for (int r = 0; r < 8; ++r) acc2[r] = bias2;
    for (int k0 = 0; k0 < HD; k0 += 32) {
#pragma unroll
        for (int i = 0; i < 16; ++i) {
            int idx = t + i * 256;
            int kk = idx >> 7, cc = idx & 127;
            Bs[kk][cc] = W2[(size_t)(k0 + kk) * HD + cc];
        }
        __syncthreads();
#pragma unroll
        for (int kk = 0; kk < 32; ++kk) {
            float bv = Bs[kk][c];
#pragma unroll
            for (int r = 0; r < 8; ++r)
                acc2[r] += hs[rh * 8 + r][k0 + kk] * bv;
        }
        __syncthreads();
    }

#pragma unroll
    for (int r = 0; r < 8; ++r) {
        int rg = row0 + rh * 8 + r;
        if (rg < Nb) out[(size_t)rg * HD + c] = acc2[r];
    }
}

extern "C" void kernel_launch(void* const* d_in, const int* in_sizes, int n_in,
                              void* d_out, int out_size, void* d_ws, size_t ws_size,
                              hipStream_t stream) {
    int iT = 0, iB = 1, iH = 2, iW = 3, iW1 = 4, ib1 = 5, ig = 6, ibe = 7,
        iW2 = 8, ib2 = 9;
    bool has_scalars = (n_in >= 10 && in_sizes[2] == 1 && in_sizes[3] == 1);
    if (!has_scalars) { iW1 = 2; ib1 = 3; ig = 4; ibe = 5; iW2 = 6; ib2 = 7; }

    const float* tokens = (const float*)d_in[iT];
    const int*   bboxes = (const int*)d_in[iB];
    const int*   pH     = has_scalars ? (const int*)d_in[iH] : nullptr;
    const int*   pW     = has_scalars ? (const int*)d_in[iW] : nullptr;
    const float* W1     = (const float*)d_in[iW1];
    const float* b1     = (const float*)d_in[ib1];
    const float* gamma  = (const float*)d_in[ig];
    const float* beta   = (const float*)d_in[ibe];
    const float* W2     = (const float*)d_in[iW2];
    const float* b2     = (const float*)d_in[ib2];
    float* out = (float*)d_out;

    int Hd = in_sizes[ib1];               // 128
    int E  = in_sizes[iW1] / Hd;          // 1024
    int Nb = in_sizes[iB] / 4;            // 4096
    int P  = in_sizes[iT] / E;            // 5476
    int npw = 1;
    while ((npw + 1) * (npw + 1) <= P) ++npw;  // 74
    int nph = P / npw;
    (void)out_size; (void)ws_size;

    // Workspace: S (2.88 MB) + 8 partial U buffers (22.4 MB) = 25.3 MB
    float* S = (float*)d_ws;
    size_t s_elems = ((size_t)(nph + 1) * (npw + 1) * HD + 255) & ~(size_t)255;
    float* U = S + s_elems;

    int mtiles = (P + 63) / 64;
    gemm_u_kernel<<<dim3(mtiles, SPLITK), dim3(256), 0, stream>>>(
        tokens, W1, U, P, E);
    prefix_x_kernel<<<dim3(nph, 2), dim3(256), (size_t)npw * 64 * 4, stream>>>(
        U, S, P, npw, nph);
    prefix_y_kernel<<<dim3(npw + 1, 2), dim3(256), (size_t)nph * 64 * 4, stream>>>(
        S, npw, nph);
    pool_proj_kernel<<<dim3((Nb + 15) / 16), dim3(256), 0, stream>>>(
        S, bboxes, pH, pW, b1, gamma, beta, W2, b2, out, Nb, npw, nph,
        14 * npw, 14 * nph);
}

// Round 7
// 133.838 us; speedup vs baseline: 2.2625x; 1.0008x over previous
//
#include <hip/hip_runtime.h>

// ---------------------------------------------------------------------------
// VisionEncoder (PASSING since R12, absmax 1.95e-3): project -> SAT -> fused
// pool/LN/GEMM2. V4 coordinate semantics (XLA reciprocal-multiply) verified.
//
// R21: extend R20's proven win (global_load_lds DMA staging, -3.9us) to the
//   remaining manual-staging sites, all bit-identical numerics:
//   - K1 As: row-major [64][32] UNPADDED -> A staging is 2 DMA calls/wave
//     (dest = wavebase + lane*16), replacing the transpose scatter (2 global
//     float4 + 8 scalar ds_writes/thread). Inner loop reads As as float4 per
//     row per kk-quad; only 2 distinct tr per wave -> <=2 addrs per LDS read
//     -> conflict-free. Per-acc kk order preserved -> bit-identical.
//   - K4 W2 staging: 16 scalar load+stores -> 4 DMA calls (dest = t*16).
//   - K3 tile staging: float4+ds_write -> DMA per 256-thread round.
//   prefix_x staging sums 8 partials (arithmetic) -> cannot DMA, unchanged.
//   K1 gemm_u  : 64x128 tile, 8x4 micro, split-K=8 -> 688 blocks
//   K2 prefix_x: grid (nph,2), 64 ch/block, sums 8 partials, x-scan -> SAT
//   K3 prefix_y: grid (npw+1,2), 64 ch/block, y-scan in LDS
//   K4 pool_proj: parallel LN stats (256-thr partial sums + LDS tree)
// ---------------------------------------------------------------------------

#define HD 128
#define SPLITK 8

#define GLOBAL_AS __attribute__((address_space(1)))
#define LDS_AS    __attribute__((address_space(3)))

__device__ __forceinline__ int decode_dim(const int* p, int fallback) {
    if (p == nullptr) return fallback;
    int vi = *p;
    if (vi >= 1 && vi <= 1000000) return vi;
    float vf = __int_as_float(vi);
    if (vf >= 1.0f && vf <= 1000000.0f) return (int)vf;
    return fallback;
}

// V4 (verified R12): trunc( fl32( fl32(x * fl32(1/W)) * n ) ), bit-exact via
// f64; optnone so no fast-math rewrite can touch it.
__attribute__((noinline, optnone))
__device__ int coord_map(int x, int W, int n) {
    double rd = 1.0 / (double)W;
    float r = (float)rd;
    double qd = (double)x * (double)r;
    float q = (float)qd;
    double pd = (double)q * (double)n;
    float p = (float)pd;
    return (int)p;
}

// ---------------------------------------------------------------------------
// K1: partial GEMM, tile 64 rows x 128 cols, K-chunk = E/8.
// Both tiles staged via global_load_lds width=16 (async DMA, drained by the
// compiler's vmcnt(0)-before-barrier).
//   As[64][32] row-major unpadded: call i, wave w, lane l covers
//     byte i*4096 + w*1024 + l*16  ==  As[i*32 + w*8 + l>>3][(l&7)*4]
//   Bs[32][128]: as R20 (verified).
// ---------------------------------------------------------------------------
__global__ __launch_bounds__(256) void gemm_u_kernel(
    const float* __restrict__ T, const float* __restrict__ W1,
    float* __restrict__ U, int P, int E)
{
    __shared__ float As[64][32];    // [row][kk] row-major, UNPADDED (DMA dest)
    __shared__ float Bs[32][HD];    // [kk][col]

    int t  = threadIdx.x;
    int tc = t & 31;                // cols tc*4 .. tc*4+3
    int tr = t >> 5;                // rows tr*8 .. tr*8+7
    int w  = t >> 6;
    int lane = t & 63;
    int row0 = blockIdx.x * 64;
    int ks   = blockIdx.y;
    int kchunk = E >> 3;            // 128
    int kbase  = ks * kchunk;
    float* Uo = U + (size_t)ks * (size_t)P * HD;

    float acc[8][4];
#pragma unroll
    for (int r = 0; r < 8; ++r)
#pragma unroll
        for (int j = 0; j < 4; ++j) acc[r][j] = 0.f;

    int a_sub = lane >> 3;          // row within 8-row group
    int a_col = (lane & 7) * 4;     // k offset
    int brow = t >> 5;              // 0..7
    int bc   = (t & 31) * 4;

    for (int kt = 0; kt < kchunk; kt += 32) {
        int k0 = kbase + kt;
        {   // stage A: 2 DMA calls per wave
#pragma unroll
            for (int i = 0; i < 2; ++i) {
                int ar = i * 32 + w * 8 + a_sub;
                int rg = row0 + ar; if (rg >= P) rg = P - 1;
                __builtin_amdgcn_global_load_lds(
                    (const GLOBAL_AS unsigned int*)&T[(size_t)rg * E + k0 + a_col],
                    (LDS_AS unsigned int*)&As[ar][a_col], 16, 0, 0);
            }
        }
        {   // stage B: 4 DMA calls per wave (verified R20)
#pragma unroll
            for (int i = 0; i < 4; ++i) {
                int kk = brow + i * 8;
                __builtin_amdgcn_global_load_lds(
                    (const GLOBAL_AS unsigned int*)&W1[(size_t)(k0 + kk) * HD + bc],
                    (LDS_AS unsigned int*)&Bs[kk][bc], 16, 0, 0);
            }
        }
        __syncthreads();

        // kk in quads; per acc[r][j] the adds run kk ascending (bit-identical
        // to the old per-kk loop).
#pragma unroll
        for (int q = 0; q < 8; ++q) {
            float4 b0 = *(const float4*)&Bs[q * 4 + 0][tc * 4];
            float4 b1 = *(const float4*)&Bs[q * 4 + 1][tc * 4];
            float4 b2 = *(const float4*)&Bs[q * 4 + 2][tc * 4];
            float4 b3 = *(const float4*)&Bs[q * 4 + 3][tc * 4];
#pragma unroll
            for (int r = 0; r < 8; ++r) {
                float4 a = *(const float4*)&As[tr * 8 + r][q * 4];
                acc[r][0] += a.x * b0.x; acc[r][1] += a.x * b0.y;
                acc[r][2] += a.x * b0.z; acc[r][3] += a.x * b0.w;
                acc[r][0] += a.y * b1.x; acc[r][1] += a.y * b1.y;
                acc[r][2] += a.y * b1.z; acc[r][3] += a.y * b1.w;
                acc[r][0] += a.z * b2.x; acc[r][1] += a.z * b2.y;
                acc[r][2] += a.z * b2.z; acc[r][3] += a.z * b2.w;
                acc[r][0] += a.w * b3.x; acc[r][1] += a.w * b3.y;
                acc[r][2] += a.w * b3.z; acc[r][3] += a.w * b3.w;
            }
        }
        __syncthreads();
    }

#pragma unroll
    for (int r = 0; r < 8; ++r) {
        int p = row0 + tr * 8 + r;
        if (p < P) {
            float4 v = make_float4(acc[r][0], acc[r][1], acc[r][2], acc[r][3]);
            *(float4*)&Uo[(size_t)p * HD + tc * 4] = v;
        }
    }
}

// ---------------------------------------------------------------------------
// K2: block (y, chalf): sum SPLITK partials of row y (74 x 64ch), x-scan,
// write SAT row y+1 (+ col-0 border). (staging sums partials -> no DMA)
// ---------------------------------------------------------------------------
__global__ __launch_bounds__(256) void prefix_x_kernel(
    const float* __restrict__ U, float* __restrict__ S,
    int P, int npw, int nph)
{
    extern __shared__ float tile[];            // npw*64 floats
    int t = threadIdx.x;
    int y = blockIdx.x;
    int ch0 = blockIdx.y * 64;
    size_t ustride = (size_t)P * HD;
    size_t ubase = (size_t)y * npw * HD + ch0;

    int nj = npw * 16;                         // float4 groups
    for (int j = t; j < nj; j += 256) {
        int x = j >> 4, cq = (j & 15) * 4;
        size_t off = ubase + (size_t)x * HD + cq;
        float4 s = *(const float4*)(U + off);
#pragma unroll
        for (int p = 1; p < SPLITK; ++p) {
            float4 v = *(const float4*)(U + (size_t)p * ustride + off);
            s.x += v.x; s.y += v.y; s.z += v.z; s.w += v.w;
        }
        *(float4*)&tile[x * 64 + cq] = s;
    }
    __syncthreads();

    if (t < 64) {
        int c = t;
        size_t srow = (size_t)(y + 1) * (npw + 1) * HD + ch0;
        S[srow + c] = 0.f;                     // col-0 border
        float acc = 0.f;
        for (int x = 0; x < npw; ++x) {
            acc += tile[x * 64 + c];
            S[srow + (size_t)(x + 1) * HD + c] = acc;
        }
    }
}

// ---------------------------------------------------------------------------
// K3: block (x, chalf): stage column x (y=1..nph) through LDS via DMA
// (dest = round*4096 + t*16, wave-uniform + lane*16), y-scan, write back.
// ---------------------------------------------------------------------------
__global__ __launch_bounds__(256) void prefix_y_kernel(
    float* __restrict__ S, int npw, int nph)
{
    extern __shared__ float tile[];            // nph*64 floats
    int t = threadIdx.x;
    int x = blockIdx.x;
    int ch0 = blockIdx.y * 64;
    size_t stride = (size_t)(npw + 1) * HD;
    size_t base = (size_t)x * HD + ch0;

    int nj = nph * 16;
    for (int j = t; j < nj; j += 256) {
        int y = j >> 4, cq = (j & 15) * 4;
        __builtin_amdgcn_global_load_lds(
            (const GLOBAL_AS unsigned int*)(S + base + (size_t)(y + 1) * stride + cq),
            (LDS_AS unsigned int*)&tile[y * 64 + cq], 16, 0, 0);
    }
    __syncthreads();

    if (t < 64) {
        int c = t;
        S[base + c] = 0.f;                     // row-0 border
        float acc = 0.f;
        for (int y = 0; y < nph; ++y) {
            acc += tile[y * 64 + c];
            S[base + (size_t)(y + 1) * stride + c] = acc;
        }
    }
}

// ---------------------------------------------------------------------------
// K4: 16 boxes x 128 cols; parallel LN stats; fp32 out. W2 staged via DMA
// (call i: dest byte = i*4096 + t*16 == Bs[i*8 + t>>5][(t&31)*4]).
// ---------------------------------------------------------------------------
__global__ __launch_bounds__(256) void pool_proj_kernel(
    const float* __restrict__ S, const int* __restrict__ bboxes,
    const int* __restrict__ pH, const int* __restrict__ pW,
    const float* __restrict__ b1, const float* __restrict__ gamma,
    const float* __restrict__ beta, const float* __restrict__ W2,
    const float* __restrict__ b2, float* __restrict__ out,
    int Nb, int npw, int nph, int fbW, int fbH)
{
    __shared__ float hs[16][HD + 1];
    __shared__ float Bs[32][HD];
    __shared__ float red_s[16][17], red_q[16][17];
    __shared__ int   cI11[16], cI12[16], cI21[16], cI22[16];
    __shared__ float cCnt[16];
    __shared__ float mu_s[16], rs_s[16];

    int t = threadIdx.x;
    int c = t & 127;
    int rh = t >> 7;
    int row0 = blockIdx.x * 16;

    if (t < 16) {
        int b = row0 + t; if (b >= Nb) b = Nb - 1;
        int x1 = bboxes[b * 4 + 0];
        int y1 = bboxes[b * 4 + 1];
        int x2 = bboxes[b * 4 + 2];
        int y2 = bboxes[b * 4 + 3];
        int Wi = decode_dim(pW, fbW);
        int Hi = decode_dim(pH, fbH);
        int px1 = coord_map(x1, Wi, npw);
        int px2 = coord_map(x2, Wi, npw);
        int py1 = coord_map(y1, Hi, nph);
        int py2 = coord_map(y2, Hi, nph);
        px1 = min(max(px1, 0), npw - 1);
        px2 = max(px1 + 1, min(px2, npw));
        py1 = min(max(py1, 0), nph - 1);
        py2 = max(py1 + 1, min(py2, nph));
        int st = npw + 1;
        cI11[t] = (py1 * st + px1) * HD;
        cI12[t] = (py1 * st + px2) * HD;
        cI21[t] = (py2 * st + px1) * HD;
        cI22[t] = (py2 * st + px2) * HD;
        cCnt[t] = (float)((py2 - py1) * (px2 - px1));
    }
    __syncthreads();

    float bias1 = b1[c];
    float hv[8];
#pragma unroll
    for (int r = 0; r < 8; ++r) {
        int row = rh * 8 + r;
        float s = S[cI22[row] + c] - S[cI12[row] + c]
                - S[cI21[row] + c] + S[cI11[row] + c];
        hv[r] = s / cCnt[row] + bias1;
        hs[row][c] = hv[r];
    }
    __syncthreads();

    // parallel LN stats: 16 threads per row, 8 elements each
    {
        int sr = t & 15;           // row
        int sg = t >> 4;           // group 0..15
        float ps = 0.f, pq = 0.f;
#pragma unroll
        for (int i = 0; i < 8; ++i) {
            float v = hs[sr][sg * 8 + i];
            ps += v; pq += v * v;
        }
        red_s[sr][sg] = ps; red_q[sr][sg] = pq;
    }
    __syncthreads();
    if (t < 16) {
        float s = 0.f, q = 0.f;
#pragma unroll
        for (int i = 0; i < 16; ++i) { s += red_s[t][i]; q += red_q[t][i]; }
        float m = s * (1.0f / HD);
        float v = q * (1.0f / HD) - m * m;
        mu_s[t] = m;
        rs_s[t] = rsqrtf(v + 1e-5f);
    }
    __syncthreads();

    float g = gamma[c], be = beta[c];
#pragma unroll
    for (int r = 0; r < 8; ++r) {
        int row = rh * 8 + r;
        float x = (hv[r] - mu_s[row]) * rs_s[row] * g + be;
        hs[row][c] = fmaxf(x, 0.f);
    }
    __syncthreads();

    float bias2 = b2[c];
    float acc2[8];
#pragma unroll
    for (int r = 0; r < 8; ++r) acc2[r] = bias2;
    for (int k0 = 0; k0 < HD; k0 += 32) {
#pragma unroll
        for (int i = 0; i < 4; ++i) {
            int kk = i * 8 + (t >> 5);
            int cc = (t & 31) * 4;
            __builtin_amdgcn_global_load_lds(
                (const GLOBAL_AS unsigned int*)&W2[(size_t)(k0 + kk) * HD + cc],
                (LDS_AS unsigned int*)&Bs[kk][cc], 16, 0, 0);
        }
        __syncthreads();
#pragma unroll
        for (int kk = 0; kk < 32; ++kk) {
            float bv = Bs[kk][c];
#pragma unroll
            for (int r = 0; r < 8; ++r)
                acc2[r] += hs[rh * 8 + r][k0 + kk] * bv;
        }
        __syncthreads();
    }

#pragma unroll
    for (int r = 0; r < 8; ++r) {
        int rg = row0 + rh * 8 + r;
        if (rg < Nb) out[(size_t)rg * HD + c] = acc2[r];
    }
}

extern "C" void kernel_launch(void* const* d_in, const int* in_sizes, int n_in,
                              void* d_out, int out_size, void* d_ws, size_t ws_size,
                              hipStream_t stream) {
    int iT = 0, iB = 1, iH = 2, iW = 3, iW1 = 4, ib1 = 5, ig = 6, ibe = 7,
        iW2 = 8, ib2 = 9;
    bool has_scalars = (n_in >= 10 && in_sizes[2] == 1 && in_sizes[3] == 1);
    if (!has_scalars) { iW1 = 2; ib1 = 3; ig = 4; ibe = 5; iW2 = 6; ib2 = 7; }

    const float* tokens = (const float*)d_in[iT];
    const int*   bboxes = (const int*)d_in[iB];
    const int*   pH     = has_scalars ? (const int*)d_in[iH] : nullptr;
    const int*   pW     = has_scalars ? (const int*)d_in[iW] : nullptr;
    const float* W1     = (const float*)d_in[iW1];
    const float* b1     = (const float*)d_in[ib1];
    const float* gamma  = (const float*)d_in[ig];
    const float* beta   = (const float*)d_in[ibe];
    const float* W2     = (const float*)d_in[iW2];
    const float* b2     = (const float*)d_in[ib2];
    float* out = (float*)d_out;

    int Hd = in_sizes[ib1];               // 128
    int E  = in_sizes[iW1] / Hd;          // 1024
    int Nb = in_sizes[iB] / 4;            // 4096
    int P  = in_sizes[iT] / E;            // 5476
    int npw = 1;
    while ((npw + 1) * (npw + 1) <= P) ++npw;  // 74
    int nph = P / npw;
    (void)out_size; (void)ws_size;

    // Workspace: S (2.88 MB) + 8 partial U buffers (22.4 MB) = 25.3 MB
    float* S = (float*)d_ws;
    size_t s_elems = ((size_t)(nph + 1) * (npw + 1) * HD + 255) & ~(size_t)255;
    float* U = S + s_elems;

    int mtiles = (P + 63) / 64;
    gemm_u_kernel<<<dim3(mtiles, SPLITK), dim3(256), 0, stream>>>(
        tokens, W1, U, P, E);
    prefix_x_kernel<<<dim3(nph, 2), dim3(256), (size_t)npw * 64 * 4, stream>>>(
        U, S, P, npw, nph);
    prefix_y_kernel<<<dim3(npw + 1, 2), dim3(256), (size_t)nph * 64 * 4, stream>>>(
        S, npw, nph);
    pool_proj_kernel<<<dim3((Nb + 15) / 16), dim3(256), 0, stream>>>(
        S, bboxes, pH, pW, b1, gamma, beta, W2, b2, out, Nb, npw, nph,
        14 * npw, 14 * nph);
}